// Round 4
// baseline (13136.865 us; speedup 1.0000x reference)
//
#include <hip/hip_runtime.h>
#include <stdint.h>

#define SEQT   512
#define HID    512
#define GRPS   8      // batch groups (32 batches each)
#define SLICES 32     // h-slices per group (16 h-indices x 4 gates = 64 gate rows each)
#define GB     32     // batches per group
#define NTHR   512

typedef __attribute__((ext_vector_type(8))) short bf16x8;
typedef __attribute__((ext_vector_type(4))) float f32x4;
typedef unsigned int uint32;

// ---- d_ws layout (bytes) ----
// [0,12582912)          packed weights: 3 matrices x (hi 2MB + lo 2MB), A-frag order
// [12582912,14680064)   packed h: h1p, h2p each [2 slot][8 grp][16384] uint (hi|lo<<16)
// [14680064,+20480)     group barrier counters [8][640] u32
#define WMAT_ELEMS 1048576
#define WS_H_OFF   12582912
#define HBUF_ELEMS 16384
#define WS_BAR_OFF 14680064
#define BAR_STRIDE 640
#define SMEM_BYTES 153600

__device__ __forceinline__ unsigned short f2bf(float x){
    unsigned int u = __float_as_uint(x);
    u = (u + 0x7fffu + ((u >> 16) & 1u)) >> 16;   // RNE
    return (unsigned short)u;
}
__device__ __forceinline__ float bf2f(unsigned short h){
    return __uint_as_float(((unsigned int)h) << 16);
}
__device__ __forceinline__ float sigm(float v){ return 1.0f / (1.0f + __expf(-v)); }
__device__ __forceinline__ float tanh_(float v){
    float e = __expf(2.0f * v);
    return (e - 1.0f) / (e + 1.0f);
}

// Pack W[2048][512] fp32 -> hi/lo bf16 in MFMA A-fragment order (unchanged from r3):
// element(jg, kt, lane, jj):  row = g*512 + j*16 + (lane&15), k = kt*32 + ((lane>>4)&3)*8 + jj
__global__ void prep_weights(const float* __restrict__ W0,
                             const float* __restrict__ W1,
                             const float* __restrict__ W2,
                             short* __restrict__ wp)
{
    const int mat = blockIdx.y;
    const float* src = (mat == 0) ? W0 : ((mat == 1) ? W1 : W2);
    short* dh = wp + (size_t)mat * (2 * WMAT_ELEMS);
    short* dl = dh + WMAT_ELEMS;
    const int jg = blockIdx.x;            // j*4 + g, 0..127
    const int j = jg >> 2, g = jg & 3;
    for (int rep = 0; rep < 2; ++rep){
        int task = rep * NTHR + (int)threadIdx.x;   // 0..1023 = (kt,lane)
        int kt = task >> 6, l = task & 63;
        int row = g * 512 + j * 16 + (l & 15);
        int k0  = kt * 32 + ((l >> 4) & 3) * 8;
        const float* s = src + (size_t)row * HID + k0;
        bf16x8 vh, vl;
        #pragma unroll
        for (int e = 0; e < 8; ++e){
            float v = s[e];
            unsigned short hb = f2bf(v);
            vh[e] = (short)hb;
            vl[e] = (short)f2bf(v - bf2f(hb));
        }
        size_t o = ((size_t)(jg * 16 + kt) * 64 + l) * 8;
        *(bf16x8*)(dh + o) = vh;
        *(bf16x8*)(dl + o) = vl;
    }
}

__global__ void __launch_bounds__(NTHR, 2)
lstm2_mfma(const float* __restrict__ x,
           const float* __restrict__ Wih0,
           const float* __restrict__ bih0, const float* __restrict__ bhh0,
           const float* __restrict__ bih1, const float* __restrict__ bhh1,
           const float* __restrict__ Wfc,  const float* __restrict__ bfc,
           float* __restrict__ out, char* __restrict__ ws)
{
    extern __shared__ char smem[];
    short* lh1h = (short*)smem;             // 16384 bf16 = 32KB (h1 hi, B-frag order)
    short* lh1l = lh1h + 16384;
    short* lh2h = lh1l + 16384;
    short* lh2l = lh2h + 16384;             // total 128KB
    float* g1   = (float*)(smem + 131072);  // [4 gate][2 n][16 q][16 b] = 8KB
    float* g2   = g1 + 2048;                // 8KB
    float* fcb  = g2 + 2048;                // [3][512] = 6KB

    const short* Wp  = (const short*)ws;
    const short* W0h = Wp;                      const short* W0l = Wp + WMAT_ELEMS;
    const short* W1h = Wp + 2 * WMAT_ELEMS;     const short* W1l = Wp + 3 * WMAT_ELEMS;
    const short* W2h = Wp + 4 * WMAT_ELEMS;     const short* W2l = Wp + 5 * WMAT_ELEMS;
    uint32* h1p_ws = (uint32*)(ws + WS_H_OFF);              // [2][8][16384] uint
    uint32* h2p_ws = h1p_ws + 2 * GRPS * HBUF_ELEMS;        // [2][8][16384] uint
    unsigned int* bar = (unsigned int*)(ws + WS_BAR_OFF);

    const int tid = threadIdx.x;
    const int wg  = blockIdx.x;
    const int grp = wg >> 5;          // 0..7   (wg&7 == j&7 -> weight slices co-locate per XCD)
    const int j   = wg & 31;          // h-slice 0..31

    // MFMA mapping: 8 waves = 4 gates x 2 k-halves
    const int wv = tid >> 6, lane = tid & 63;
    const int g  = wv >> 1, kh = wv & 1;
    const int ablk = (j * 4 + g) * 16;

    // pointwise mapping: 16 q x 32 b
    const int q  = tid >> 5, b = tid & 31;
    const int qg = j * 16 + q;
    const int nn = b >> 4, bl = b & 15;
    // B-frag element index of h(k=qg, col=b)
    const int eidx = (((qg >> 5) * 2 + nn) * 64 + ((qg >> 3) & 3) * 16 + bl) * 8 + (qg & 7);

    float bias1[4], bias2[4], wxr[4][3];
    #pragma unroll
    for (int gg = 0; gg < 4; ++gg){
        int row = gg * 512 + qg;
        bias1[gg] = bih0[row] + bhh0[row];
        bias2[gg] = bih1[row] + bhh1[row];
        wxr[gg][0] = Wih0[row * 3 + 0];
        wxr[gg][1] = Wih0[row * 3 + 1];
        wxr[gg][2] = Wih0[row * 3 + 2];
    }
    const float wf0 = Wfc[qg], wf1 = Wfc[512 + qg], wf2 = Wfc[1024 + qg];

    // ---- pin hi-weights in VGPRs (96 VGPRs; constant-indexed via full unroll) ----
    bf16x8 w0h[8], w1h[8], w2h[8];
    #pragma unroll
    for (int ks = 0; ks < 8; ++ks){
        const int kt = kh * 8 + ks;
        const size_t ao = ((size_t)(ablk + kt) * 64 + lane) * 8;
        w0h[ks] = *(const bf16x8*)(W0h + ao);
        w1h[ks] = *(const bf16x8*)(W1h + ao);
        w2h[ks] = *(const bf16x8*)(W2h + ao);
    }

    float c1 = 0.f, c2 = 0.f;

    // phase p: L1 computes t=p (p<512); L2 computes t=p-1 (p>=1). One barrier/phase.
    for (int p = 0; p <= SEQT; ++p){
        const int rs1 = (p + 1) & 1;   // slot of h1(p-1)
        const int rs2 = p & 1;         // slot of h2(p-2)

        // ---- stage packed h1(p-1), h2(p-2) into LDS, unpacking hi/lo (coherent loads) ----
        {
            const unsigned long long* s1 =
                (const unsigned long long*)(h1p_ws + (rs1 * GRPS + grp) * HBUF_ELEMS);
            const unsigned long long* s2 =
                (const unsigned long long*)(h2p_ws + (rs2 * GRPS + grp) * HBUF_ELEMS);
            uint32* d1h = (uint32*)lh1h; uint32* d1l = (uint32*)lh1l;
            uint32* d2h = (uint32*)lh2h; uint32* d2l = (uint32*)lh2l;

            unsigned long long v[16];
            #pragma unroll
            for (int c = 0; c < 16; ++c)
                v[c] = __hip_atomic_load(s1 + c * 512 + tid,
                                         __ATOMIC_RELAXED, __HIP_MEMORY_SCOPE_AGENT);
            #pragma unroll
            for (int c = 0; c < 16; ++c){
                uint32 a = (uint32)v[c], bo_ = (uint32)(v[c] >> 32);
                d1h[c * 512 + tid] = __builtin_amdgcn_perm(bo_, a, 0x05040100u); // low16s
                d1l[c * 512 + tid] = __builtin_amdgcn_perm(bo_, a, 0x07060302u); // high16s
            }
            #pragma unroll
            for (int c = 0; c < 16; ++c)
                v[c] = __hip_atomic_load(s2 + c * 512 + tid,
                                         __ATOMIC_RELAXED, __HIP_MEMORY_SCOPE_AGENT);
            #pragma unroll
            for (int c = 0; c < 16; ++c){
                uint32 a = (uint32)v[c], bo_ = (uint32)(v[c] >> 32);
                d2h[c * 512 + tid] = __builtin_amdgcn_perm(bo_, a, 0x05040100u);
                d2l[c * 512 + tid] = __builtin_amdgcn_perm(bo_, a, 0x07060302u);
            }
        }
        __syncthreads();

        // ---- MFMA: gates1 = Whh0*h1 ; gates2 = Wih1*h1 + Whh1*h2 (bf16 3-mul split) ----
        f32x4 acc1[2] = {{0.f,0.f,0.f,0.f},{0.f,0.f,0.f,0.f}};
        f32x4 acc2[2] = {{0.f,0.f,0.f,0.f},{0.f,0.f,0.f,0.f}};
        #pragma unroll
        for (int ks = 0; ks < 8; ++ks){
            const int kt = kh * 8 + ks;
            const size_t ao = ((size_t)(ablk + kt) * 64 + lane) * 8;
            bf16x8 a0l = *(const bf16x8*)(W0l + ao);   // lo-halves stream from (now-warm) L2
            bf16x8 a1l = *(const bf16x8*)(W1l + ao);
            bf16x8 a2l = *(const bf16x8*)(W2l + ao);
            #pragma unroll
            for (int n = 0; n < 2; ++n){
                const int bo = ((kt * 2 + n) * 64 + lane) * 8;
                bf16x8 b1h = *(const bf16x8*)(lh1h + bo);
                bf16x8 b1l = *(const bf16x8*)(lh1l + bo);
                bf16x8 b2h = *(const bf16x8*)(lh2h + bo);
                bf16x8 b2l = *(const bf16x8*)(lh2l + bo);
                acc1[n] = __builtin_amdgcn_mfma_f32_16x16x32_bf16(w0h[ks], b1h, acc1[n], 0, 0, 0);
                acc1[n] = __builtin_amdgcn_mfma_f32_16x16x32_bf16(w0h[ks], b1l, acc1[n], 0, 0, 0);
                acc1[n] = __builtin_amdgcn_mfma_f32_16x16x32_bf16(a0l,     b1h, acc1[n], 0, 0, 0);
                acc2[n] = __builtin_amdgcn_mfma_f32_16x16x32_bf16(w1h[ks], b1h, acc2[n], 0, 0, 0);
                acc2[n] = __builtin_amdgcn_mfma_f32_16x16x32_bf16(w1h[ks], b1l, acc2[n], 0, 0, 0);
                acc2[n] = __builtin_amdgcn_mfma_f32_16x16x32_bf16(a1l,     b1h, acc2[n], 0, 0, 0);
                acc2[n] = __builtin_amdgcn_mfma_f32_16x16x32_bf16(w2h[ks], b2h, acc2[n], 0, 0, 0);
                acc2[n] = __builtin_amdgcn_mfma_f32_16x16x32_bf16(w2h[ks], b2l, acc2[n], 0, 0, 0);
                acc2[n] = __builtin_amdgcn_mfma_f32_16x16x32_bf16(a2l,     b2h, acc2[n], 0, 0, 0);
            }
        }

        // ---- combine k-halves in LDS ----
        if (kh == 0){
            #pragma unroll
            for (int n = 0; n < 2; ++n)
                #pragma unroll
                for (int r = 0; r < 4; ++r){
                    int qrow = (lane >> 4) * 4 + r;
                    int idx = ((g * 2 + n) * 16 + qrow) * 16 + (lane & 15);
                    g1[idx] = acc1[n][r];
                    g2[idx] = acc2[n][r];
                }
        }
        __syncthreads();
        if (kh == 1){
            #pragma unroll
            for (int n = 0; n < 2; ++n)
                #pragma unroll
                for (int r = 0; r < 4; ++r){
                    int qrow = (lane >> 4) * 4 + r;
                    int idx = ((g * 2 + n) * 16 + qrow) * 16 + (lane & 15);
                    g1[idx] += acc1[n][r];
                    g2[idx] += acc2[n][r];
                }
        }
        __syncthreads();

        // ---- pointwise L1 (t = p): packed coherent h-store ----
        if (p < SEQT){
            float gt0 = bias1[0] + g1[((0 * 2 + nn) * 16 + q) * 16 + bl];
            float gt1 = bias1[1] + g1[((1 * 2 + nn) * 16 + q) * 16 + bl];
            float gt2 = bias1[2] + g1[((2 * 2 + nn) * 16 + q) * 16 + bl];
            float gt3 = bias1[3] + g1[((3 * 2 + nn) * 16 + q) * 16 + bl];
            const float* xp = x + ((size_t)(grp * GB + b) * SEQT + p) * 3;
            float x0 = xp[0], x1 = xp[1], x2 = xp[2];
            gt0 += wxr[0][0] * x0 + wxr[0][1] * x1 + wxr[0][2] * x2;
            gt1 += wxr[1][0] * x0 + wxr[1][1] * x1 + wxr[1][2] * x2;
            gt2 += wxr[2][0] * x0 + wxr[2][1] * x1 + wxr[2][2] * x2;
            gt3 += wxr[3][0] * x0 + wxr[3][1] * x1 + wxr[3][2] * x2;
            float ii = sigm(gt0), ff = sigm(gt1), gv = tanh_(gt2), oo = sigm(gt3);
            c1 = ff * c1 + ii * gv;
            float h = oo * tanh_(c1);
            unsigned short hb = f2bf(h);
            unsigned short lb = f2bf(h - bf2f(hb));
            uint32 pv = (uint32)hb | ((uint32)lb << 16);
            __hip_atomic_store(h1p_ws + ((p & 1) * GRPS + grp) * HBUF_ELEMS + eidx, pv,
                               __ATOMIC_RELAXED, __HIP_MEMORY_SCOPE_AGENT);
        }

        // ---- pointwise L2 (t = p-1) + FC partials ----
        if (p >= 1){
            float gt0 = bias2[0] + g2[((0 * 2 + nn) * 16 + q) * 16 + bl];
            float gt1 = bias2[1] + g2[((1 * 2 + nn) * 16 + q) * 16 + bl];
            float gt2 = bias2[2] + g2[((2 * 2 + nn) * 16 + q) * 16 + bl];
            float gt3 = bias2[3] + g2[((3 * 2 + nn) * 16 + q) * 16 + bl];
            float ii = sigm(gt0), ff = sigm(gt1), gv = tanh_(gt2), oo = sigm(gt3);
            c2 = ff * c2 + ii * gv;
            float h = oo * tanh_(c2);
            unsigned short hb = f2bf(h);
            unsigned short lb = f2bf(h - bf2f(hb));
            uint32 pv = (uint32)hb | ((uint32)lb << 16);
            __hip_atomic_store(h2p_ws + (((p - 1) & 1) * GRPS + grp) * HBUF_ELEMS + eidx, pv,
                               __ATOMIC_RELAXED, __HIP_MEMORY_SCOPE_AGENT);
            fcb[0 * 512 + tid] = wf0 * h;
            fcb[1 * 512 + tid] = wf1 * h;
            fcb[2 * 512 + tid] = wf2 * h;
        }
        __syncthreads();
        if (p >= 1 && tid < 96){
            int d = tid >> 5, bb = tid & 31;
            float s = 0.f;
            #pragma unroll
            for (int qq = 0; qq < 16; ++qq) s += fcb[d * 512 + qq * 32 + bb];
            if (j == 0) s += bfc[d];
            atomicAdd(out + ((size_t)(grp * GB + bb) * SEQT + (p - 1)) * 3 + d, s);
        }

        // ---- group barrier (32 WGs of this batch group); release orders h-stores.
        // No acquire fence: all cross-WG data is read via agent-scope atomic loads,
        // which bypass (possibly stale) L1/L2 -> weights stay L2-resident across phases.
        if (tid == 0){
            unsigned int* c = bar + grp * BAR_STRIDE + p;
            __hip_atomic_fetch_add(c, 1u, __ATOMIC_RELEASE, __HIP_MEMORY_SCOPE_AGENT);
            while (__hip_atomic_load(c, __ATOMIC_RELAXED, __HIP_MEMORY_SCOPE_AGENT) < (unsigned)SLICES) {}
        }
        __syncthreads();
    }
}

extern "C" void kernel_launch(void* const* d_in, const int* in_sizes, int n_in,
                              void* d_out, int out_size, void* d_ws, size_t ws_size,
                              hipStream_t stream)
{
    (void)in_sizes; (void)n_in; (void)ws_size;

    const float* x    = (const float*)d_in[0];
    const float* Wih0 = (const float*)d_in[1];
    const float* Whh0 = (const float*)d_in[2];
    const float* bih0 = (const float*)d_in[3];
    const float* bhh0 = (const float*)d_in[4];
    const float* Wih1 = (const float*)d_in[5];
    const float* Whh1 = (const float*)d_in[6];
    const float* bih1 = (const float*)d_in[7];
    const float* bhh1 = (const float*)d_in[8];
    const float* Wfc  = (const float*)d_in[9];
    const float* bfc  = (const float*)d_in[10];
    float* out = (float*)d_out;
    char*  ws  = (char*)d_ws;

    // zero packed-h buffers + barrier counters (contiguous), and the atomic output
    hipMemsetAsync(ws + WS_H_OFF, 0, (WS_BAR_OFF - WS_H_OFF) + GRPS * BAR_STRIDE * sizeof(unsigned int), stream);
    hipMemsetAsync(d_out, 0, (size_t)out_size * sizeof(float), stream);

    // pack weights into MFMA fragment order (d_ws is re-poisoned before every launch)
    prep_weights<<<dim3(128, 3), NTHR, 0, stream>>>(Whh0, Wih1, Whh1, (short*)ws);

    hipFuncSetAttribute((const void*)lstm2_mfma,
                        hipFuncAttributeMaxDynamicSharedMemorySize, SMEM_BYTES);

    void* args[] = { (void*)&x, (void*)&Wih0, (void*)&bih0, (void*)&bhh0,
                     (void*)&bih1, (void*)&bhh1, (void*)&Wfc, (void*)&bfc,
                     (void*)&out, (void*)&ws };
    hipLaunchCooperativeKernel((const void*)lstm2_mfma, dim3(GRPS * SLICES), dim3(NTHR),
                               args, SMEM_BYTES, stream);
}